// Round 2
// baseline (78.969 us; speedup 1.0000x reference)
//
#include <hip/hip_runtime.h>

#define NB 4
#define NC 32
#define HW 4096
#define NW 64

#define PPT 4              // pixels per thread (contiguous)
#define TPB 256            // threads per block
#define PPB (PPT * TPB)    // 1024 pixels per block
#define TILES (HW / PPB)   // 4 tiles per (b,c)

// d_ws layout: [0..NW)            float4 tab  : {cf, -2cf*mr, -2cf*mi, cf*(mr^2+mi^2)}
//              [NW*4 .. +NC*NW*2) float2 wtab : {wr, wi} per (c,k)
__global__ __launch_bounds__(TPB) void rbf_prep(
    const float* __restrict__ w_real, const float* __restrict__ w_imag,
    const float* __restrict__ mu_real, const float* __restrict__ mu_imag,
    const float* __restrict__ stddev,
    float4* __restrict__ tab, float2* __restrict__ wtab)
{
    const int t = blockIdx.x * blockDim.x + threadIdx.x;
    if (t < NW) {
        const float cf = -1.4426950408889634f / (2.0f * stddev[t]);
        const float mr = mu_real[t];
        const float mi = mu_imag[t];
        tab[t] = make_float4(cf, -2.0f * cf * mr, -2.0f * cf * mi,
                             cf * (mr * mr + mi * mi));
    }
    if (t < NC * NW) {
        wtab[t] = make_float2(w_real[t], w_imag[t]);
    }
}

__global__ __launch_bounds__(TPB) void rbf_main(
    const float* __restrict__ x_real, const float* __restrict__ x_imag,
    const float* __restrict__ b_real, const float* __restrict__ b_imag,
    const float4* __restrict__ tab, const float2* __restrict__ wtab,
    float* __restrict__ out)
{
    const int bc   = blockIdx.x / TILES;      // b*NC + c
    const int tile = blockIdx.x % TILES;
    const int c    = bc & (NC - 1);
    const int t    = threadIdx.x;

    const int blockBase = bc * HW + tile * PPB;   // first pixel of this block

    // ---- vector loads: 4 contiguous pixels per thread ----
    const float4 xr4 = reinterpret_cast<const float4*>(x_real + blockBase)[t];
    const float4 xi4 = reinterpret_cast<const float4*>(x_imag + blockBase)[t];
    const float xr[PPT] = {xr4.x, xr4.y, xr4.z, xr4.w};
    const float xi[PPT] = {xi4.x, xi4.y, xi4.z, xi4.w};

    float n2[PPT];
#pragma unroll
    for (int p = 0; p < PPT; ++p)
        n2[p] = fmaf(xr[p], xr[p], xi[p] * xi[p]);

    const float br = b_real[c];   // uniform -> s_load
    const float bi = b_imag[c];

    float ar[PPT], ai[PPT];
#pragma unroll
    for (int p = 0; p < PPT; ++p) { ar[p] = br; ai[p] = bi; }

    const float2* __restrict__ wrow = wtab + c * NW;   // uniform base

#pragma unroll 8
    for (int k = 0; k < NW; ++k) {
        const float4 row = tab[k];    // uniform -> s_load_dwordx4 {cf, a, b, cconst}
        const float2 w   = wrow[k];   // uniform -> s_load_dwordx2 {wr, wi}
#pragma unroll
        for (int p = 0; p < PPT; ++p) {
            float e = fmaf(row.x, n2[p], row.w);   // cf*n2 + cconst
            e = fmaf(row.y, xr[p], e);             // + a*xr
            e = fmaf(row.z, xi[p], e);             // + b*xi
            const float r = __builtin_amdgcn_exp2f(e);
            ar[p] = fmaf(r, w.x, ar[p]);
            ai[p] = fmaf(r, w.y, ai[p]);
        }
    }

    // ---- vector stores: pixels are contiguous, (re,im) interleaved ----
    float4* __restrict__ out4 = reinterpret_cast<float4*>(out + 2 * blockBase);
    out4[2 * t + 0] = make_float4(ar[0], ai[0], ar[1], ai[1]);
    out4[2 * t + 1] = make_float4(ar[2], ai[2], ar[3], ai[3]);
}

extern "C" void kernel_launch(void* const* d_in, const int* in_sizes, int n_in,
                              void* d_out, int out_size, void* d_ws, size_t ws_size,
                              hipStream_t stream) {
    const float* x_real  = (const float*)d_in[0];
    const float* x_imag  = (const float*)d_in[1];
    const float* w_real  = (const float*)d_in[2];
    const float* w_imag  = (const float*)d_in[3];
    const float* b_real  = (const float*)d_in[4];
    const float* b_imag  = (const float*)d_in[5];
    const float* mu_real = (const float*)d_in[6];
    const float* mu_imag = (const float*)d_in[7];
    const float* stddev  = (const float*)d_in[8];
    float* out = (float*)d_out;

    float4* tab  = (float4*)d_ws;
    float2* wtab = (float2*)((char*)d_ws + NW * sizeof(float4));

    rbf_prep<<<(NC * NW + TPB - 1) / TPB, TPB, 0, stream>>>(
        w_real, w_imag, mu_real, mu_imag, stddev, tab, wtab);

    const int grid = NB * NC * TILES;  // 512 blocks
    rbf_main<<<grid, TPB, 0, stream>>>(x_real, x_imag, b_real, b_imag,
                                       tab, wtab, out);
}